// Round 6
// baseline (552.040 us; speedup 1.0000x reference)
//
#include <hip/hip_runtime.h>

// Stacked LSTM B=2048,T=512,IN=4,H=64,L=4,OUT=5 — R15 champion (509us) +
// sync-scaffolding reduction. Scoreboard: R10 603 / R11 639 / R12 713 /
// R13 965 / R14 540 / R15 509us (MfmaUtil 44.5%, VALUBusy 63.6%).
// R15 wall = 2386 cyc/SIMD/step: MFMA issue 1062, VALU issue 1517, ~870
// latency-exposed. Useful VALU is only ~900/SIMD (16 trans + ~50 scalar
// per lane-step) -> ~600 cyc/SIMD is POLL MACHINERY (2 poll loops/step,
// ~10 ops/iter, 2-3 spins on partner handshake, x4 waves). This round:
//  1. ONE combined poll per step (was 2): lanes 0-2 partners>=t, 3-6
//     next>=t-3 (l<3), 7-10 prev>=t+1 (l>0). Same monotone conditions,
//     same ring proofs, half the machinery.
//  2. monotone flag CACHING: a lane reloads its flag only if cached <
//     target. Prev/next watchers (drift slack) skip the atomic most
//     steps; partners reload once/step.
//  3. batched A-reads: all 4 ds_reads issue back-to-back after the poll
//     (A2,A3,A0,A1 = first-needed first) -> one lgkm latency window.
// MFMA accumulation order UNCHANGED (kt2 with C=bias, kt3, kt0, kt1) ->
// bit-identical math to R15 (absmax 4.9e-4): f16 weights+acts, prescale
// -log2e (i,f,o) / +2log2e (g) -> direct exp2; fused gate products
// (8 trans/update); scaled cell state C'=2log2e*c; bias in MFMA C-operand.
// Ring (R14-proven): 16 waves, depth-4 slot ring, identity-k layout rows
// 128 B XOR-swizzled ((r&7)<<4 both sides); input(t) of layer l read from
// layer l-1's own-h slot (t+1)&3. Flag deps before step t: partners >= t,
// prev >= t+1, next >= t-3 (WAR). A-frag: row=lane&15 (batch),
// k=(lane>>4)*8+e (unit, identity). C: col=lane&15 (unit),
// row=(lane>>4)*4+reg (rows 4q+rr, rr<2 real, batch b=2q+rr).

#define B_    2048
#define T_    512
#define H_    64
#define OUT_  5
#define LOG2E 1.44269504088896340736f

typedef _Float16 f16;
typedef __attribute__((ext_vector_type(4))) _Float16 f16x4;
typedef __attribute__((ext_vector_type(8))) _Float16 f16x8;
typedef __attribute__((ext_vector_type(4))) float f32x4;
typedef __attribute__((ext_vector_type(2))) unsigned long long u64x2;

__device__ __forceinline__ float rcpf(float v) { return __builtin_amdgcn_rcpf(v); }
__device__ __forceinline__ float ex2(float v)  { return __builtin_amdgcn_exp2f(v); }

__global__ __launch_bounds__(1024, 4) void lstm_ring4_k(
    const float* __restrict__ x,      // [B,T,4]
    const float* __restrict__ W_ih0,  // [256,4]
    const float* __restrict__ W_ihr,  // [3,256,64]
    const float* __restrict__ W_hh,   // [4,256,64]
    const float* __restrict__ b_ih,   // [4,256]
    const float* __restrict__ b_hh,   // [4,256]
    const float* __restrict__ W_fc,   // [5,64]
    const float* __restrict__ b_fc,   // [5]
    float* __restrict__ out)          // [B,5]
{
    const int tid  = threadIdx.x;
    const int wave = tid >> 6;        // 0..15
    const int l    = wave >> 2;       // layer 0..3
    const int jj   = wave & 3;        // quarter of the layer's units
    const int lane = tid & 63;
    const int q    = lane >> 4;
    const int ln   = lane & 15;
    const int b0   = blockIdx.x * 8;

    // [layer][slot 0..3][16 rows x 64 f16], row=128 B, XOR-swizzled. 32 KB.
    __shared__ f16  hbuf[4][4][1024];
    __shared__ f16  xlds[T_][8][4];    // 32 KB
    __shared__ float hf[8][H_ + 1];    // FC staging
    __shared__ int  flg[16];

    for (int k = tid; k < 8192; k += 1024) ((unsigned*)hbuf)[k] = 0u;
    if (tid < 16) flg[tid] = 0;

    // ---- one-time x preload -> xlds (f16), coalesced float4 reads ----
#pragma unroll
    for (int k = 0; k < 4; ++k) {
        const int idx = tid + k * 1024;              // 0..4095
        const int bb  = idx >> 9, tt = idx & 511;
        const float4 v = *(const float4*)(x + (size_t)(b0 + bb) * (T_ * 4) + tt * 4);
        f16x4 h4; h4[0] = (f16)v.x; h4[1] = (f16)v.y; h4[2] = (f16)v.z; h4[3] = (f16)v.w;
        *(f16x4*)&xlds[tt][bb][0] = h4;
    }

    // ---- weights -> f16 B-frags (4 gates x 4 kt = 64 VGPR), prescaled ----
    const float* Whh = W_hh + (size_t)l * 256 * 64;
    const float* Wih = (l == 0) ? W_ih0 : (W_ihr + (size_t)(l - 1) * 256 * 64);
    const float scg[4] = {-LOG2E, -LOG2E, 2.0f * LOG2E, -LOG2E};

    f16x8 Wf[4][4];                   // [gate][kt]; kt0/1 = h, kt2/3 = input
    f32x4 Cb[4];                      // bias as MFMA C-init (broadcast rows)
#pragma unroll
    for (int g4 = 0; g4 < 4; ++g4) {
        const int n = g4 * 64 + jj * 16 + ln;
        const float bv = (b_ih[l * 256 + n] + b_hh[l * 256 + n]) * scg[g4];
        Cb[g4][0] = bv; Cb[g4][1] = bv; Cb[g4][2] = bv; Cb[g4][3] = bv;
#pragma unroll
        for (int kt = 0; kt < 4; ++kt) {
            f16x8 f;
#pragma unroll
            for (int e = 0; e < 8; ++e) {
                float wv;
                if (kt < 2)      wv = Whh[n * 64 + kt * 32 + q * 8 + e];
                else if (l == 0) wv = (kt == 2 && q == 0 && e < 4) ? Wih[n * 4 + e] : 0.0f;
                else             wv = Wih[n * 64 + (kt - 2) * 32 + q * 8 + e];
                f[e] = (f16)(wv * scg[g4]);
            }
            Wf[g4][kt] = f;
        }
    }

    // ---- per-lane LDS byte offsets (swizzled) ----
    const int swz   = (ln & 7) << 4;
    const int roffA = (ln * 128 + q * 16) ^ swz;        // k-octets 0..3
    const int roffB = (ln * 128 + 64 + q * 16) ^ swz;   // k-octets 4..7
    char* ownB      = (char*)&hbuf[l][0][0];
    const char* prvB = (const char*)&hbuf[(l > 0) ? (l - 1) : 0][0][0];

    int woff[2];
#pragma unroll
    for (int rr = 0; rr < 2; ++rr) {
        const int r = 4 * q + rr;
        woff[rr] = (r * 128 + (jj * 16 + ln) * 2) ^ ((r & 7) << 4);
    }
    const int  xb  = 2 * (ln >> 2) + (ln & 1);      // batch for x-frag row ln
    const bool xok = (q == 0) && ((ln & 3) < 2);    // real batch rows only

    // ---- combined flag-watch lane map (ONE poll/step) ----
    // lanes 0..2: partners >= t; 3..6: next >= t-3 (l<3); 7..10: prev >= t+1 (l>0)
    int fIdx = 0, fOff = 0; bool fUse = false;
    if (lane < 3)                        { fIdx = 4 * l + ((jj + 1 + lane) & 3); fOff = 0;  fUse = true; }
    else if (lane < 7 && l < 3)          { fIdx = 4 * (l + 1) + (lane - 3);      fOff = -3; fUse = true; }
    else if (lane >= 7 && lane < 11 && l > 0) { fIdx = 4 * (l - 1) + (lane - 7); fOff = 1;  fUse = true; }

    __syncthreads();                  // zero-init + xlds + flg visible

    float cst[2] = {0.f, 0.f};        // SCALED cell state C' = 2log2e * c
    const float K2 = 2.0f * LOG2E;
    int fc = fUse ? 0 : 0x7fffffff;   // cached flag value (monotone)

    auto body = [&](const int t, const int sl, const int sn) {
        // ---- single combined poll (cached, monotone) ----
        {
            const int tgt = t + fOff;
            unsigned g = 0;
            for (;;) {
                if (fUse && fc < tgt)
                    fc = __hip_atomic_load(&flg[fIdx], __ATOMIC_ACQUIRE,
                                           __HIP_MEMORY_SCOPE_WORKGROUP);
                if (__all(fc >= tgt)) break;
                if (++g > 4) __builtin_amdgcn_s_sleep(1);
                if (g > (1u << 16)) break;           // degrade, don't hang
            }
        }

        // ---- all A-frag reads, first-needed first ----
        f16x8 A2, A3;
        if (l > 0) {
            const char* ri = prvB + sn * 2048;       // h_{l-1}(t)
            A2 = *(const f16x8*)(ri + roffA);
            A3 = *(const f16x8*)(ri + roffB);
        } else {
            unsigned long long xw = 0ull;
            if (xok) xw = *(const unsigned long long*)&xlds[t][xb][0];
            u64x2 tmp; tmp[0] = xw; tmp[1] = 0ull;
            A2 = __builtin_bit_cast(f16x8, tmp);     // x(t) @ k=64..67
            A3 = A2;                                  // unused
        }
        const char* ro = ownB + sl * 2048;           // h_l(t-1)
        const f16x8 A0 = *(const f16x8*)(ro + roffA);
        const f16x8 A1 = *(const f16x8*)(ro + roffB);

        // ---- 16 (12) MFMA, exact R15 order: kt2(C=bias), kt3, kt0, kt1 ----
        __builtin_amdgcn_s_setprio(1);
        f32x4 acc[4];
#pragma unroll
        for (int g4 = 0; g4 < 4; ++g4)
            acc[g4] = __builtin_amdgcn_mfma_f32_16x16x32_f16(A2, Wf[g4][2], Cb[g4], 0, 0, 0);
        if (l > 0) {                                 // kt3 identically 0 for l==0
#pragma unroll
            for (int g4 = 0; g4 < 4; ++g4)
                acc[g4] = __builtin_amdgcn_mfma_f32_16x16x32_f16(A3, Wf[g4][3], acc[g4], 0, 0, 0);
        }
#pragma unroll
        for (int g4 = 0; g4 < 4; ++g4)
            acc[g4] = __builtin_amdgcn_mfma_f32_16x16x32_f16(A0, Wf[g4][0], acc[g4], 0, 0, 0);
#pragma unroll
        for (int g4 = 0; g4 < 4; ++g4)
            acc[g4] = __builtin_amdgcn_mfma_f32_16x16x32_f16(A1, Wf[g4][1], acc[g4], 0, 0, 0);

        // ---- pointwise: 8 trans/update (fused), scaled cell state ----
        char* wr = ownB + sn * 2048;                 // h(t) -> slot (t+1)&3
#pragma unroll
        for (int rr = 0; rr < 2; ++rr) {
            const float Ei = ex2(acc[0][rr]);        // e^{-i}
            const float Ef = ex2(acc[1][rr]);        // e^{-f}
            const float Eg = ex2(acc[2][rr]);        // e^{+2g}
            const float Eo = ex2(acc[3][rr]);        // e^{-o}
            const float sf   = rcpf(1.0f + Ef);                  // sigmoid(f)
            const float di   = (1.0f + Ei) * (1.0f + Eg);
            const float sitg = fmaf(Eg, K2, -K2) * rcpf(di);     // 2log2e*si*tg
            const float Cp   = fmaf(sf, cst[rr], sitg);          // C'=2log2e*c
            cst[rr] = Cp;
            const float Ec = ex2(Cp);                // e^{+2c}
            const float dc = (1.0f + Eo) * (1.0f + Ec);
            const float h  = (Ec - 1.0f) * rcpf(dc); // sigmoid(o)*tanh(c)
            *(f16*)(wr + woff[rr]) = (f16)h;
            if (l == 3 && t == T_ - 1) hf[2 * q + rr][jj * 16 + ln] = h;
        }
        __builtin_amdgcn_s_setprio(0);

        if (lane == 0)                // release: drains LDS writes first
            __hip_atomic_store(&flg[wave], t + 1, __ATOMIC_RELEASE,
                               __HIP_MEMORY_SCOPE_WORKGROUP);
    };

#pragma unroll 1
    for (int t = 0; t < T_; t += 4) {                // slots folded to constants
        body(t,     0, 1);
        body(t + 1, 1, 2);
        body(t + 2, 2, 3);
        body(t + 3, 3, 0);
    }

    // ---- FC on h(T-1) of layer 3 ----
    __syncthreads();
    if (tid < 8 * OUT_) {
        const int b = tid / OUT_, o = tid % OUT_;
        float a = b_fc[o];
#pragma unroll
        for (int k = 0; k < H_; ++k)
            a = fmaf(hf[b][k], W_fc[o * H_ + k], a);
        out[(b0 + b) * OUT_ + o] = a;
    }
}

extern "C" void kernel_launch(void* const* d_in, const int* in_sizes, int n_in,
                              void* d_out, int out_size, void* d_ws, size_t ws_size,
                              hipStream_t stream) {
    const float* x     = (const float*)d_in[0];
    const float* W_ih0 = (const float*)d_in[1];
    const float* W_ihr = (const float*)d_in[2];
    const float* W_hh  = (const float*)d_in[3];
    const float* b_ih  = (const float*)d_in[4];
    const float* b_hh  = (const float*)d_in[5];
    const float* W_fc  = (const float*)d_in[6];
    const float* b_fc  = (const float*)d_in[7];
    float* out = (float*)d_out;

    lstm_ring4_k<<<dim3(B_ / 8), dim3(1024), 0, stream>>>(
        x, W_ih0, W_ihr, W_hh, b_ih, b_hh, W_fc, b_fc, out);
}